// Round 1
// baseline (1034.741 us; speedup 1.0000x reference)
//
#include <hip/hip_runtime.h>
#include <stdint.h>

#define D_DIM   768
#define N_DIM   2304
#define M_DIM   65536
#define BM      128
#define BN      128
#define BK      32

typedef short v8ss __attribute__((ext_vector_type(8)));
typedef float v4f  __attribute__((ext_vector_type(4)));

__device__ __forceinline__ unsigned short f2bf(float f) {
    union { float f; uint32_t u; } v; v.f = f;
    uint32_t r = v.u + 0x7fffu + ((v.u >> 16) & 1u);   // RNE
    return (unsigned short)(r >> 16);
}

// ---------------------------------------------------------------------------
// Kernel 1: W_eff[e][k] = W[e][k] + LoRA rank-4 update, cast to bf16.
//   e in [0,768):        += s0 * sum_r B_q[e][r] * A_q[r][k]
//   e in [1536,2304):    += s0 * sum_r B_v[e-1536][r] * A_v[r][k]
// ---------------------------------------------------------------------------
__global__ void prep_w(const float* __restrict__ W,
                       const float* __restrict__ Aq, const float* __restrict__ Bq,
                       const float* __restrict__ Av, const float* __restrict__ Bv,
                       const float* __restrict__ s0,
                       unsigned short* __restrict__ Weff) {
    int idx = blockIdx.x * 256 + threadIdx.x;      // 0 .. 2304*768-1 (exact)
    int e = idx / D_DIM;
    int k = idx - e * D_DIM;
    float w = W[idx];
    float s = s0[0];
    if (e < D_DIM) {
        float acc = 0.f;
#pragma unroll
        for (int r = 0; r < 4; r++) acc += Bq[e * 4 + r] * Aq[r * D_DIM + k];
        w += s * acc;
    } else if (e >= 2 * D_DIM) {
        int d = e - 2 * D_DIM;
        float acc = 0.f;
#pragma unroll
        for (int r = 0; r < 4; r++) acc += Bv[d * 4 + r] * Av[r * D_DIM + k];
        w += s * acc;
    }
    Weff[idx] = f2bf(w);
}

// ---------------------------------------------------------------------------
// Kernel 2: x fp32 -> bf16 (vectorized, grid-stride)
// ---------------------------------------------------------------------------
__global__ void convert_x(const float* __restrict__ x,
                          unsigned short* __restrict__ xb, int n4) {
    int stride = gridDim.x * blockDim.x;
    for (int i = blockIdx.x * blockDim.x + threadIdx.x; i < n4; i += stride) {
        float4 v = ((const float4*)x)[i];
        ushort4 o;
        o.x = f2bf(v.x); o.y = f2bf(v.y); o.z = f2bf(v.z); o.w = f2bf(v.w);
        ((ushort4*)xb)[i] = o;
    }
}

// ---------------------------------------------------------------------------
// Kernel 3: GEMM  C[M,N] = Abf16[M,K] * Weff^T[K,N] + bias[N]
//   A row-major M x K (bf16), Weff row-major N x K (bf16, "B^T" layout).
//   128x128 block tile, 4 waves (2x2), BK=32, mfma_f32_16x16x32_bf16.
//   XB16=true : A staged via global_load_lds from pre-converted bf16 buffer.
//   XB16=false: A loaded fp32 from x, converted in-regs, ds_write staged.
// ---------------------------------------------------------------------------
template <bool XB16>
__global__ __launch_bounds__(256, 2) void gemm_bt(const void* __restrict__ Aptr,
                                                  const unsigned short* __restrict__ Weff,
                                                  const float* __restrict__ bias,
                                                  float* __restrict__ out) {
    __shared__ __align__(16) unsigned short As[BM * BK];   // 8 KB, 64B rows
    __shared__ __align__(16) unsigned short Bs[BN * BK];   // 8 KB

    const int tid = threadIdx.x;
    const int l   = tid & 63;
    const int w   = tid >> 6;          // wave id 0..3
    const int wm  = w & 1;             // wave M position (0/1)
    const int wn  = w >> 1;            // wave N position (0/1)
    const int n0  = blockIdx.x * BN;
    const int m0  = blockIdx.y * BM;

    v4f acc[4][4];
#pragma unroll
    for (int i = 0; i < 4; i++)
#pragma unroll
        for (int j = 0; j < 4; j++) acc[i][j] = (v4f){0.f, 0.f, 0.f, 0.f};

    const int lq  = l >> 4;            // quad 0..3
    const int l15 = l & 15;

    for (int k0 = 0; k0 < D_DIM; k0 += BK) {
        __syncthreads();   // prior iter's ds_reads complete before overwrite

        if (XB16) {
            const unsigned short* xb = (const unsigned short*)Aptr;
#pragma unroll
            for (int c = 0; c < 2; c++) {
                int mloc = c * 64 + w * 16 + (l >> 2);
                int kloc = (l & 3) * 8;
                const unsigned short* g = xb + (size_t)(m0 + mloc) * D_DIM + k0 + kloc;
                __builtin_amdgcn_global_load_lds(
                    (const __attribute__((address_space(1))) void*)g,
                    (__attribute__((address_space(3))) void*)(As + c * 2048 + w * 512),
                    16, 0, 0);
            }
        } else {
            const float* x = (const float*)Aptr;
#pragma unroll
            for (int p = 0; p < 4; p++) {
                int row = p * 32 + (tid >> 3);
                int kk  = (tid & 7) * 4;
                float4 v = *(const float4*)(x + (size_t)(m0 + row) * D_DIM + k0 + kk);
                ushort4 o;
                o.x = f2bf(v.x); o.y = f2bf(v.y); o.z = f2bf(v.z); o.w = f2bf(v.w);
                *(ushort4*)&As[row * BK + kk] = o;
            }
        }

#pragma unroll
        for (int c = 0; c < 2; c++) {
            int nloc = c * 64 + w * 16 + (l >> 2);
            int kloc = (l & 3) * 8;
            const unsigned short* g = Weff + (size_t)(n0 + nloc) * D_DIM + k0 + kloc;
            __builtin_amdgcn_global_load_lds(
                (const __attribute__((address_space(1))) void*)g,
                (__attribute__((address_space(3))) void*)(Bs + c * 2048 + w * 512),
                16, 0, 0);
        }

        __syncthreads();   // drains vmcnt -> staged tiles visible

        v8ss a_frag[4], b_frag[4];
#pragma unroll
        for (int mt = 0; mt < 4; mt++)
            a_frag[mt] = *(const v8ss*)&As[(wm * 64 + mt * 16 + l15) * BK + lq * 8];
#pragma unroll
        for (int nt = 0; nt < 4; nt++)
            b_frag[nt] = *(const v8ss*)&Bs[(wn * 64 + nt * 16 + l15) * BK + lq * 8];

#pragma unroll
        for (int mt = 0; mt < 4; mt++)
#pragma unroll
            for (int nt = 0; nt < 4; nt++)
                acc[mt][nt] = __builtin_amdgcn_mfma_f32_16x16x32_bf16(
                    a_frag[mt], b_frag[nt], acc[mt][nt], 0, 0, 0);
    }

    // Epilogue: C/D layout col = l&15, row = (l>>4)*4 + i   [m89-verified]
#pragma unroll
    for (int nt = 0; nt < 4; nt++) {
        int col = n0 + wn * 64 + nt * 16 + l15;
        float bv = bias[col];
#pragma unroll
        for (int mt = 0; mt < 4; mt++) {
            int row = m0 + wm * 64 + mt * 16 + lq * 4;
            float* o = out + (size_t)row * N_DIM + col;
#pragma unroll
            for (int i = 0; i < 4; i++)
                o[(size_t)i * N_DIM] = acc[mt][nt][i] + bv;
        }
    }
}

// ---------------------------------------------------------------------------
extern "C" void kernel_launch(void* const* d_in, const int* in_sizes, int n_in,
                              void* d_out, int out_size, void* d_ws, size_t ws_size,
                              hipStream_t stream) {
    const float* x   = (const float*)d_in[0];
    const float* W   = (const float*)d_in[1];
    const float* b   = (const float*)d_in[2];
    const float* Aq  = (const float*)d_in[3];
    const float* Bq  = (const float*)d_in[4];
    const float* Av  = (const float*)d_in[5];
    const float* Bv  = (const float*)d_in[6];
    const float* s0  = (const float*)d_in[7];
    float* out = (float*)d_out;

    unsigned short* Weff = (unsigned short*)d_ws;
    const size_t weff_elems = (size_t)N_DIM * D_DIM;            // 1,769,472
    const size_t x_elems    = (size_t)M_DIM * D_DIM;            // 50,331,648
    const size_t need       = weff_elems * 2 + x_elems * 2;     // ~99.4 MiB

    prep_w<<<(int)(weff_elems / 256), 256, 0, stream>>>(W, Aq, Bq, Av, Bv, s0, Weff);

    dim3 grid(N_DIM / BN, M_DIM / BM);   // 18 x 512
    if (ws_size >= need) {
        unsigned short* xb = Weff + weff_elems;
        convert_x<<<4096, 256, 0, stream>>>(x, xb, (int)(x_elems / 4));
        gemm_bt<true><<<grid, 256, 0, stream>>>(xb, Weff, b, out);
    } else {
        gemm_bt<false><<<grid, 256, 0, stream>>>(x, Weff, b, out);
    }
}